// Round 4
// baseline (545.129 us; speedup 1.0000x reference)
//
#include <hip/hip_runtime.h>

// LSTM anomaly detector: B=4096, T=512, I=3, H=64 (4H=256 gates)
// One block = 16 batch rows, 4 waves, grid=256 (1 block/CU).
// Wave w owns cols [w*16,w*16+16) of all four gates -> lane-local i,f,g,o.
// R4:
//  - x path removed from MFMA: per-lane fp32 xg = x@W_ih^T + bias (48 FMA)
//    seeds the MFMA C operand. MFMA/step: 36 -> 24 per wave.
//  - xg for step t+1 computed right after issuing step t's MFMAs (manual
//    software pipeline; fills the MFMA shadow).
//  - decoder rotates across waves (w == t&3), bias via C-seed.
//  - h exchange: producer-side trunc-split into bf16 hi/lo LDS (ds_read_b128
//    rebuild, zero VALU), double-buffered on t-parity, 1 barrier/step.

#define TLEN 512
#define TCHUNK 64

typedef float  float4_t __attribute__((ext_vector_type(4)));
typedef __bf16 bf16x8   __attribute__((ext_vector_type(8)));

__device__ __forceinline__ float fexp2(float x){ return __builtin_amdgcn_exp2f(x); }
__device__ __forceinline__ float frcp (float x){ return __builtin_amdgcn_rcpf(x); }
__device__ __forceinline__ float sigm (float x){ return frcp(1.f + fexp2(-1.44269504f*x)); }
__device__ __forceinline__ float tanh_(float x){ return 1.f - 2.f*frcp(1.f + fexp2(2.88539008f*x)); }

// setup-only RNE split (weights; cost irrelevant)
__device__ __forceinline__ void split8(const float* v, bf16x8& hi, bf16x8& lo){
  #pragma unroll
  for (int j = 0; j < 8; j++){
    __bf16 h = (__bf16)v[j];
    hi[j] = h;
    lo[j] = (__bf16)(v[j] - (float)h);
  }
}

#define MFMA(a,b,c) __builtin_amdgcn_mfma_f32_16x16x32_bf16((a),(b),(c),0,0,0)

// ---- LDS layout ----
// ushort region (bf16 h exchange):
#define HHI 0        // 2 x [16 rows][72]  (double-buffered, stride 72 -> 16B rows)
#define HLO 2304
#define HS_SZ 4608
// float region:
#define XOF 0        // [16 rows][196] fp32 x staging (row-major, 192 used)
#define OOF 3136     // [16 rows][196] fp32 out staging
#define XP4 6272     // [64 t][16 rows][4] fp32 packed {x0,x1,x2,-}
#define LF_SZ 10368

__global__ __launch_bounds__(256, 1)
void LSTMAnomalyDetector_kernel(
    const float* __restrict__ x,     const float* __restrict__ W_ih,
    const float* __restrict__ W_hh,  const float* __restrict__ b_ih,
    const float* __restrict__ b_hh,  const float* __restrict__ W_dec,
    const float* __restrict__ b_dec, float* __restrict__ out)
{
  __shared__ __align__(16) unsigned short HS[HS_SZ];
  __shared__ __align__(16) float          LF[LF_SZ];

  const int tid  = threadIdx.x;
  const int w    = tid >> 6;        // wave 0..3
  const int lane = tid & 63;
  const int q    = lane >> 4;       // quad 0..3
  const int lid  = lane & 15;
  const int b0   = blockIdx.x * 16; // batch rows [b0, b0+16)
  const int cw   = w*16 + lid;      // this lane's H-column

  // ---- resident weight fragments (B-operand: B[k=kt*32+q*8+j][n=lid]) ----
  bf16x8 Bh[4][2], Bl[4][2];  // W_hh^T hi/lo; tl = gate type (i,f,g,o)
  bf16x8 Dh[2],    Dl[2];     // decoder: W_dec^T (cols 0..2 valid)
  float  Wi0[4], Wi1[4], Wi2[4], bia[4];   // W_ih cols + fused bias (fp32)

  #pragma unroll
  for (int tl = 0; tl < 4; tl++){
    const int g = tl*64 + cw;                   // gate row (W_hh[256][64] row-major)
    #pragma unroll
    for (int kt = 0; kt < 2; kt++){
      const float* p = W_hh + g*64 + kt*32 + q*8;
      float v[8];
      #pragma unroll
      for (int j = 0; j < 8; j++) v[j] = p[j];
      split8(v, Bh[tl][kt], Bl[tl][kt]);
    }
    Wi0[tl] = W_ih[g*3+0];
    Wi1[tl] = W_ih[g*3+1];
    Wi2[tl] = W_ih[g*3+2];
    bia[tl] = b_ih[g] + b_hh[g];
  }
  #pragma unroll
  for (int kt = 0; kt < 2; kt++){
    float v[8] = {0.f,0.f,0.f,0.f,0.f,0.f,0.f,0.f};
    if (lid < 3){
      const float* p = W_dec + lid*64 + kt*32 + q*8;
      #pragma unroll
      for (int j = 0; j < 8; j++) v[j] = p[j];
    }
    split8(v, Dh[kt], Dl[kt]);
  }
  const float bdec = (lid < 3) ? b_dec[lid] : 0.f;

  // ---- state ----
  bf16x8 ah[2] = {}, al[2] = {};             // A-frags of h_{t-1} (hi/lo); h_{-1}=0
  float creg[4] = {0.f, 0.f, 0.f, 0.f};      // c for (row q*4+r, col cw)
  float4_t xg[4];                            // gate seeds for step t (tl-indexed, r in vec)

  // ---- preload + pack x chunk 0, compute xg for t=0 ----
  #pragma unroll
  for (int s = 0; s < 3; s++){
    const int f = tid + 256*s; const int row = f/48; const int off = (f%48)*4;
    float4_t v = *(const float4_t*)(x + (size_t)(b0+row)*1536 + off);
    *(float4_t*)&LF[XOF + row*196 + off] = v;
  }
  __syncthreads();
  #pragma unroll
  for (int s = 0; s < 4; s++){
    const int p = tid + 256*s;                 // (t,row): t=p>>4, row=p&15
    const float* xp = &LF[XOF + (p & 15)*196 + (p >> 4)*3];
    float4_t v = {xp[0], xp[1], xp[2], 0.f};
    *(float4_t*)&LF[XP4 + p*4] = v;
  }
  __syncthreads();
  #pragma unroll
  for (int r = 0; r < 4; r++){
    const float4_t xv = *(const float4_t*)&LF[XP4 + (q*4+r)*4];
    #pragma unroll
    for (int tl = 0; tl < 4; tl++)
      xg[tl][r] = __builtin_fmaf(xv[0], Wi0[tl],
                  __builtin_fmaf(xv[1], Wi1[tl],
                  __builtin_fmaf(xv[2], Wi2[tl], bia[tl])));
  }

  for (int t = 0; t < TLEN; ++t){
    const int dt = t & (TCHUNK-1);
    const int hb = (t & 1) * 1152;

    // gate preacts: MFMA chains seeded with fp32 xg (4 independent chains)
    float4_t g4[4];
    #pragma unroll
    for (int tl = 0; tl < 4; tl++){
      float4_t a = xg[tl];
      a = MFMA(ah[0], Bh[tl][0], a);
      a = MFMA(ah[1], Bh[tl][1], a);
      a = MFMA(al[0], Bh[tl][0], a);
      a = MFMA(al[1], Bh[tl][1], a);
      a = MFMA(ah[0], Bl[tl][0], a);
      a = MFMA(ah[1], Bl[tl][1], a);
      g4[tl] = a;
    }

    // software pipeline: xg for step t+1 (independent of MFMA results;
    // scheduler fills the MFMA shadow with this)
    float4_t nxg[4];
    if (dt != TCHUNK-1){
      #pragma unroll
      for (int r = 0; r < 4; r++){
        const float4_t xv = *(const float4_t*)&LF[XP4 + ((dt+1)*16 + q*4+r)*4];
        #pragma unroll
        for (int tl = 0; tl < 4; tl++)
          nxg[tl][r] = __builtin_fmaf(xv[0], Wi0[tl],
                       __builtin_fmaf(xv[1], Wi1[tl],
                       __builtin_fmaf(xv[2], Wi2[tl], bia[tl])));
      }
    }

    // lane-local activations + c/h update; producer-side trunc-split of h
    #pragma unroll
    for (int r = 0; r < 4; r++){
      const float ig = sigm (g4[0][r]);
      const float fg = sigm (g4[1][r]);
      const float gg = tanh_(g4[2][r]);
      const float og = sigm (g4[3][r]);
      creg[r] = fg*creg[r] + ig*gg;
      const float h = og * tanh_(creg[r]);
      const unsigned u  = __float_as_uint(h);
      const float    lf = h - __uint_as_float(u & 0xFFFF0000u);   // exact
      const int m = q*4 + r;
      HS[HHI + hb + m*72 + cw] = (unsigned short)(u >> 16);
      HS[HLO + hb + m*72 + cw] = (unsigned short)(__float_as_uint(lf) >> 16);
    }
    __syncthreads();   // the ONE barrier per step

    // rebuild h A-frags: 4 raw ds_read_b128, zero VALU
    {
      const unsigned short* ph = &HS[HHI + hb + lid*72 + q*8];
      const unsigned short* pl = &HS[HLO + hb + lid*72 + q*8];
      ah[0] = *(const bf16x8*)&ph[0];
      ah[1] = *(const bf16x8*)&ph[32];
      al[0] = *(const bf16x8*)&pl[0];
      al[1] = *(const bf16x8*)&pl[32];
    }

    // decoder, rotating wave: out_t = h_t @ W_dec^T + b_dec -> OOF staging
    if (w == (t & 3)){
      float4_t d = {bdec, bdec, bdec, bdec};
      d = MFMA(ah[0], Dh[0], d);
      d = MFMA(ah[1], Dh[1], d);
      d = MFMA(al[0], Dh[0], d);
      d = MFMA(al[1], Dh[1], d);
      d = MFMA(ah[0], Dl[0], d);
      d = MFMA(ah[1], Dl[1], d);
      if (lid < 3){
        #pragma unroll
        for (int r = 0; r < 4; r++)
          LF[OOF + (q*4+r)*196 + dt*3 + lid] = d[r];
      }
    }

    // chunk boundary: flush out, stage+pack next x chunk, xg for next dt=0
    if (dt == TCHUNK-1){
      __syncthreads();
      const int t0 = t - (TCHUNK-1);
      #pragma unroll
      for (int s = 0; s < 3; s++){
        const int f = tid + 256*s; const int row = f/48; const int off = (f%48)*4;
        float4_t v = *(const float4_t*)&LF[OOF + row*196 + off];
        *(float4_t*)(out + (size_t)(b0+row)*1536 + t0*3 + off) = v;
      }
      if (t + 1 < TLEN){
        #pragma unroll
        for (int s = 0; s < 3; s++){
          const int f = tid + 256*s; const int row = f/48; const int off = (f%48)*4;
          float4_t v = *(const float4_t*)(x + (size_t)(b0+row)*1536 + (t+1)*3 + off);
          *(float4_t*)&LF[XOF + row*196 + off] = v;
        }
        __syncthreads();
        #pragma unroll
        for (int s = 0; s < 4; s++){
          const int p = tid + 256*s;
          const float* xp = &LF[XOF + (p & 15)*196 + (p >> 4)*3];
          float4_t v = {xp[0], xp[1], xp[2], 0.f};
          *(float4_t*)&LF[XP4 + p*4] = v;
        }
        __syncthreads();
        #pragma unroll
        for (int r = 0; r < 4; r++){
          const float4_t xv = *(const float4_t*)&LF[XP4 + (q*4+r)*4];
          #pragma unroll
          for (int tl = 0; tl < 4; tl++)
            nxg[tl][r] = __builtin_fmaf(xv[0], Wi0[tl],
                         __builtin_fmaf(xv[1], Wi1[tl],
                         __builtin_fmaf(xv[2], Wi2[tl], bia[tl])));
        }
      }
    }

    #pragma unroll
    for (int tl = 0; tl < 4; tl++) xg[tl] = nxg[tl];
  }
}

extern "C" void kernel_launch(void* const* d_in, const int* in_sizes, int n_in,
                              void* d_out, int out_size, void* d_ws, size_t ws_size,
                              hipStream_t stream)
{
  const float* x     = (const float*)d_in[0];
  const float* W_ih  = (const float*)d_in[1];
  const float* W_hh  = (const float*)d_in[2];
  const float* b_ih  = (const float*)d_in[3];
  const float* b_hh  = (const float*)d_in[4];
  const float* W_dec = (const float*)d_in[5];
  const float* b_dec = (const float*)d_in[6];
  float* out = (float*)d_out;

  const int B = in_sizes[0] / (TLEN * 3);   // 4096
  const int blocks = B / 16;                // 256
  hipLaunchKernelGGL(LSTMAnomalyDetector_kernel, dim3(blocks), dim3(256), 0, stream,
                     x, W_ih, W_hh, b_ih, b_hh, W_dec, b_dec, out);
}